// Round 4
// baseline (358.598 us; speedup 1.0000x reference)
//
#include <hip/hip_runtime.h>
#include <hip/hip_fp16.h>
#include <stdint.h>

#define NN 100000
#define NE 1250000
#define DD 64
#define NL 4

#define NPART3 256           // partitions; one WG owns one partition in fillD
#define PSIZE3 391           // nodes per partition (256*391 = 100096 >= NN)
#define TILE4 1024           // int4s per radix tile = 4096 edges
#define NTB ((NE / 4 + TILE4 - 1) / TILE4)        // 306 tiles
#define SCANA_N (NPART3 * NTB)                    // 78336
#define SRCBITS 17           // src < 100000 < 2^17; dlocal < 391 < 2^9

#define MB2 64               // nodes per MFMA layer block
#define L2BLOCKS ((NN + MB2 - 1) / MB2)   // 1563
#define APAD 136             // halfs per A/Bt LDS row
#define CPADH 72             // halfs per C row
#define CPADF 68             // floats per C row

typedef _Float16 half8 __attribute__((ext_vector_type(8)));
typedef _Float16 half2v __attribute__((ext_vector_type(2)));
typedef float floatx4 __attribute__((ext_vector_type(4)));
typedef int intx4 __attribute__((ext_vector_type(4)));

__device__ __forceinline__ unsigned f2h2(float a, float b) {
    __half2 h = __floats2half2_rn(a, b);
    return *reinterpret_cast<unsigned*>(&h);
}
// packed fp16 max on raw bits (maps to v_pk_max_f16)
__device__ __forceinline__ unsigned umax2(unsigned a, unsigned b) {
    half2v x = *reinterpret_cast<half2v*>(&a);
    half2v y = *reinterpret_cast<half2v*>(&b);
    half2v r = __builtin_elementwise_max(x, y);
    return *reinterpret_cast<unsigned*>(&r);
}

// ---- x (fp32) -> hh4 (fp16, SLICED layout) ----
// sliced layout: half index ((s*NN + n)*16 + c), s = col/16, c = col%16.
// Each 3.2 MB slice fits a 4 MiB per-XCD L2 -> L2-resident gathers in agg.
__global__ __launch_bounds__(256) void cast_kernel(const float* __restrict__ x,
                                                   __half* __restrict__ hh4) {
    int i = blockIdx.x * 256 + threadIdx.x;   // 4-half chunk id
    float4 v = ((const float4*)x)[i];
    uint2 u;
    u.x = f2h2(v.x, v.y);
    u.y = f2h2(v.z, v.w);
    int j = i * 4;            // half index in row-major
    int n = j >> 6;
    int col = j & 63;
    int s = col >> 4;
    int c = col & 15;         // 0,4,8,12
    ((uint2*)hh4)[((size_t)s * NN + n) * 4 + (c >> 2)] = u;
}

// ---------------- radix bucketing: edges -> 256 dst-partition buckets ----------------
__global__ __launch_bounds__(256) void countA_kernel(const int* __restrict__ dst,
                                                     int* __restrict__ blockcnt) {
    __shared__ int cnt[NPART3];
    int tid = threadIdx.x;
    cnt[tid] = 0;
    __syncthreads();
    int b = blockIdx.x;
    #pragma unroll
    for (int r = 0; r < 4; ++r) {
        int i4 = b * TILE4 + r * 256 + tid;
        if (i4 < NE / 4) {
            intx4 d = __builtin_nontemporal_load(&((const intx4*)dst)[i4]);
            atomicAdd(&cnt[(unsigned)d.x / PSIZE3], 1);
            atomicAdd(&cnt[(unsigned)d.y / PSIZE3], 1);
            atomicAdd(&cnt[(unsigned)d.z / PSIZE3], 1);
            atomicAdd(&cnt[(unsigned)d.w / PSIZE3], 1);
        }
    }
    __syncthreads();
    blockcnt[tid * NTB + b] = cnt[tid];
}

// ---- parallel scan, stage 1: each WG exclusive-scans its own 306-tile row ----
__global__ __launch_bounds__(512) void scanP1_kernel(int* __restrict__ blockcnt,
                                                     int* __restrict__ rowsum) {
    __shared__ int sm[512];
    int p = blockIdx.x;
    int tid = threadIdx.x;
    int v = (tid < NTB) ? blockcnt[p * NTB + tid] : 0;
    sm[tid] = v;
    __syncthreads();
    for (int off = 1; off < 512; off <<= 1) {
        int t = (tid >= off) ? sm[tid - off] : 0;
        __syncthreads();
        sm[tid] += t;
        __syncthreads();
    }
    if (tid < NTB) blockcnt[p * NTB + tid] = sm[tid] - v;   // exclusive in-row
    if (tid == 511) rowsum[p] = sm[511];                    // row total
}

// ---- parallel scan, stage 2: exclusive scan of the 256 row totals (in place) ----
__global__ __launch_bounds__(256) void scanP2_kernel(int* __restrict__ rowsum) {
    __shared__ int sm[256];
    int tid = threadIdx.x;
    int v = rowsum[tid];
    sm[tid] = v;
    __syncthreads();
    for (int off = 1; off < 256; off <<= 1) {
        int t = (tid >= off) ? sm[tid - off] : 0;
        __syncthreads();
        sm[tid] += t;
        __syncthreads();
    }
    rowsum[tid] = sm[tid] - v;    // rowoff: global start of partition tid
}

// scatter packed (dlocal<<17 | src) into bucket order — one store per edge
__global__ __launch_bounds__(256) void scatterA_kernel(const int* __restrict__ src,
                                                       const int* __restrict__ dst,
                                                       const int* __restrict__ blockcnt,
                                                       const int* __restrict__ rowoff,
                                                       int* __restrict__ ebufP) {
    __shared__ int cur[NPART3];
    int tid = threadIdx.x;
    int b = blockIdx.x;
    cur[tid] = rowoff[tid] + blockcnt[tid * NTB + b];
    __syncthreads();
    #pragma unroll
    for (int r = 0; r < 4; ++r) {
        int i4 = b * TILE4 + r * 256 + tid;
        if (i4 < NE / 4) {
            intx4 d = __builtin_nontemporal_load(&((const intx4*)dst)[i4]);
            intx4 s = __builtin_nontemporal_load(&((const intx4*)src)[i4]);
            int part, p;
            part = (unsigned)d.x / PSIZE3; p = atomicAdd(&cur[part], 1);
            ebufP[p] = ((d.x - part * PSIZE3) << SRCBITS) | s.x;
            part = (unsigned)d.y / PSIZE3; p = atomicAdd(&cur[part], 1);
            ebufP[p] = ((d.y - part * PSIZE3) << SRCBITS) | s.y;
            part = (unsigned)d.z / PSIZE3; p = atomicAdd(&cur[part], 1);
            ebufP[p] = ((d.z - part * PSIZE3) << SRCBITS) | s.z;
            part = (unsigned)d.w / PSIZE3; p = atomicAdd(&cur[part], 1);
            ebufP[p] = ((d.w - part * PSIZE3) << SRCBITS) | s.w;
        }
    }
}

// ---- one WG per partition: LDS hist -> in-WG scan -> row_start + csr ----
__global__ __launch_bounds__(1024) void fillD_kernel(const int* __restrict__ ebufP,
                                                     const int* __restrict__ rowoff,
                                                     int* __restrict__ row_start,
                                                     int* __restrict__ csr) {
    __shared__ int cnt[PSIZE3];
    __shared__ int localstart[PSIZE3];
    __shared__ int partial[1024];
    int part = blockIdx.x;
    int tid = threadIdx.x;
    int nbase = part * PSIZE3;
    int base = rowoff[part];
    int hi = (part < NPART3 - 1) ? rowoff[part + 1] : NE;

    if (tid < PSIZE3) cnt[tid] = 0;
    __syncthreads();

    for (int i = base + tid; i < hi; i += 1024)
        atomicAdd(&cnt[(unsigned)ebufP[i] >> SRCBITS], 1);
    __syncthreads();

    int e0 = (tid < PSIZE3) ? cnt[tid] : 0;
    int s = e0;
    partial[tid] = s;
    __syncthreads();
    for (int off = 1; off < 1024; off <<= 1) {
        int v = (tid >= off) ? partial[tid - off] : 0;
        __syncthreads();
        partial[tid] += v;
        __syncthreads();
    }
    int run = partial[tid] - s;
    if (tid < PSIZE3) localstart[tid] = run;
    __syncthreads();

    int nmax = NN - nbase; if (nmax > PSIZE3) nmax = PSIZE3;
    if (tid < nmax) row_start[nbase + tid] = base + localstart[tid];
    if (part == NPART3 - 1 && tid == 0) row_start[NN] = NE;

    if (tid < PSIZE3) cnt[tid] = 0;
    __syncthreads();

    for (int i = base + tid; i < hi; i += 1024) {
        int p = ebufP[i];
        int dl = (unsigned)p >> SRCBITS;
        int local = atomicAdd(&cnt[dl], 1);
        csr[base + localstart[dl] + local] = p & ((1 << SRCBITS) - 1);
    }
}

// ---------------- per-layer gather-max, SLICED (L2-resident per pass) ----------------
// grid = (NN/16, 4): blockIdx.y = feature slice (3.2 MB table, fits per-XCD L2;
// x-fastest dispatch keeps the machine on one slice at a time).
// Wave = 4 nodes x 8 slots x 2 lanes (16 B each): one load inst gathers 32
// edge-slices. First 16 neighbors via preloaded csr row + shfl; rest direct.
__global__ __launch_bounds__(256) void agg_kernel(const __half* __restrict__ hh4,
                                                  const int* __restrict__ row_start,
                                                  const int* __restrict__ csr,
                                                  __half* __restrict__ agg4) {
    int tid = threadIdx.x;
    int wv = tid >> 6;              // wave 0..3
    int lane = tid & 63;
    int nq = lane >> 4;             // node quarter 0..3
    int l16 = lane & 15;
    int sl = l16 >> 1;              // neighbor slot 0..7
    int sub = lane & 1;             // which 16 B half of the 32 B slice row
    int s = blockIdx.y;             // slice 0..3
    int n = blockIdx.x * 16 + wv * 4 + nq;   // NN = 6250*16 exactly

    int base = row_start[n];
    int cnt  = row_start[n + 1] - base;
    int cl = cnt - 1;

    // preload first 16 neighbor indices of this node (nontemporal: keep slice in L2)
    int idx16 = 0;
    if (cnt > 0) idx16 = __builtin_nontemporal_load(&csr[base + ((l16 <= cl) ? l16 : cl)]);

    const __half* tab = hh4 + (size_t)s * NN * 16;

    const uint4 NI4 = make_uint4(0xFC00FC00u, 0xFC00FC00u, 0xFC00FC00u, 0xFC00FC00u);
    uint4 acc = (cnt > 0) ? NI4 : make_uint4(0, 0, 0, 0);

    // wave-uniform loop bound: max cnt among this wave's 4 nodes
    int km = cnt;
    km = max(km, __shfl_xor(km, 16, 64));
    km = max(km, __shfl_xor(km, 32, 64));

    for (int k = 0; k < km; k += 8) {
        int ka = k + sl;
        int srcv;
        if (k < 16) {               // wave-uniform branch
            int cka = (ka <= cl) ? ka : cl;
            if (cka < 0) cka = 0;   // cnt==0 nodes: valid shfl lane, load guarded off
            srcv = __shfl(idx16, (nq << 4) + cka, 64);
        } else {
            srcv = (ka < cnt) ? __builtin_nontemporal_load(&csr[base + ka]) : 0;
        }
        if (ka < cnt) {
            uint4 u = *(const uint4*)&tab[(size_t)srcv * 16 + sub * 8];
            acc.x = umax2(acc.x, u.x); acc.y = umax2(acc.y, u.y);
            acc.z = umax2(acc.z, u.z); acc.w = umax2(acc.w, u.w);
        }
    }

    // reduce across the 8 slots (xor 2,4,8) within each 16-lane quarter
    #pragma unroll
    for (int off = 2; off <= 8; off <<= 1) {
        acc.x = umax2(acc.x, (unsigned)__shfl_xor((int)acc.x, off, 64));
        acc.y = umax2(acc.y, (unsigned)__shfl_xor((int)acc.y, off, 64));
        acc.z = umax2(acc.z, (unsigned)__shfl_xor((int)acc.z, off, 64));
        acc.w = umax2(acc.w, (unsigned)__shfl_xor((int)acc.w, off, 64));
    }
    if (l16 < 2) {
        *(uint4*)&agg4[((size_t)s * NN + n) * 16 + sub * 8] = acc;
    }
}

// ---------------- dense update via MFMA (sliced feature I/O) ----------------
__global__ __launch_bounds__(256, 4) void layer_mfma_kernel(
        const __half* __restrict__ agg4,
        __half* __restrict__ hh4,
        float* __restrict__ hout,
        const float* __restrict__ Wl,
        const float* __restrict__ bl,
        const float* __restrict__ Wr,
        int last) {
    __shared__ char smem[2 * MB2 * APAD * 2];   // 34816 B, reused by epilogue
    _Float16* a_s  = (_Float16*)smem;                          // [64][APAD]
    _Float16* bt_s = (_Float16*)(smem + MB2 * APAD * 2);       // [64][APAD], n-major

    int tid = threadIdx.x;
    int lane = tid & 63;
    int w = tid >> 6;
    int node0 = blockIdx.x * MB2;

    #pragma unroll
    for (int i = 0; i < 4; ++i) {
        int idx = i * 256 + tid;          // uint4 id, 1024 total
        int r = idx >> 4;
        int c4 = idx & 15;
        int node = node0 + r; if (node > NN - 1) node = NN - 1;
        const __half* srcp;
        if (c4 < 8) srcp = agg4 + ((size_t)(c4 >> 1) * NN + node) * 16 + (c4 & 1) * 8;
        else {
            int cc = c4 - 8;
            srcp = hh4 + ((size_t)(cc >> 1) * NN + node) * 16 + (cc & 1) * 8;
        }
        uint4 v = *(const uint4*)srcp;
        *(uint4*)&a_s[r * APAD + c4 * 8] = v;
    }
    {
        int n = tid & 63;
        int kb = tid >> 6;
        #pragma unroll
        for (int kk = 0; kk < 32; ++kk) {
            int k = kb * 32 + kk;
            float wv = (k < 64) ? Wl[k * DD + n] : Wr[(k - 64) * DD + n];
            bt_s[n * APAD + k] = (_Float16)wv;
        }
    }
    __syncthreads();

    floatx4 acc[4];
    #pragma unroll
    for (int nt = 0; nt < 4; ++nt) acc[nt] = (floatx4){0.f, 0.f, 0.f, 0.f};
    int m = lane & 15;
    int q = lane >> 4;

    #pragma unroll
    for (int ks = 0; ks < 4; ++ks) {
        half8 af = *(half8*)&a_s[(w * 16 + m) * APAD + q * 8 + ks * 32];
        #pragma unroll
        for (int nt = 0; nt < 4; ++nt) {
            half8 bf = *(half8*)&bt_s[(nt * 16 + m) * APAD + q * 8 + ks * 32];
            acc[nt] = __builtin_amdgcn_mfma_f32_16x16x32_f16(af, bf, acc[nt], 0, 0, 0);
        }
    }
    __syncthreads();

    _Float16* ch = (_Float16*)smem;                      // [64][CPADH]
    float*    cf = (float*)(smem + MB2 * CPADH * 2);     // [64][CPADF]

    #pragma unroll
    for (int nt = 0; nt < 4; ++nt) {
        int col = nt * 16 + m;
        float b = bl[col];
        #pragma unroll
        for (int r = 0; r < 4; ++r) {
            int rowl = w * 16 + q * 4 + r;
            float o = fmaxf(acc[nt][r] + b, 0.0f);
            if (last) cf[rowl * CPADF + col] = o;
            else      ch[rowl * CPADH + col] = (_Float16)o;
        }
    }
    __syncthreads();

    if (!last) {
        #pragma unroll
        for (int i = 0; i < 2; ++i) {
            int idx = i * 256 + tid;          // 512 uint4s
            int r = idx >> 3;
            int c4 = idx & 7;
            int node = node0 + r;
            if (node < NN) {
                uint4 v = *(uint4*)&ch[r * CPADH + c4 * 8];
                *(uint4*)&hh4[((size_t)(c4 >> 1) * NN + node) * 16 + (c4 & 1) * 8] = v;
            }
        }
    } else {
        #pragma unroll
        for (int i = 0; i < 4; ++i) {
            int idx = i * 256 + tid;      // 1024 float4s
            int r = idx >> 4;
            int c4 = idx & 15;
            int node = node0 + r;
            if (node < NN) {
                float4 v = *(float4*)&cf[r * CPADF + c4 * 4];
                *(float4*)&hout[(size_t)node * DD + c4 * 4] = v;
            }
        }
    }
}

extern "C" void kernel_launch(void* const* d_in, const int* in_sizes, int n_in,
                              void* d_out, int out_size, void* d_ws, size_t ws_size,
                              hipStream_t stream) {
    const float* x  = (const float*)d_in[0];
    const int*   ei = (const int*)d_in[1];
    const float* Wl = (const float*)d_in[2];
    const float* bl = (const float*)d_in[3];
    const float* Wr = (const float*)d_in[4];
    float* h = (float*)d_out;

    const int* src = ei;
    const int* dst = ei + NE;

    char* ws = (char*)d_ws;
    __half* agg4     = (__half*)ws;  ws += (size_t)NN * DD * sizeof(__half);  // 12.8 MB
    __half* hh4      = (__half*)ws;  ws += (size_t)NN * DD * sizeof(__half);  // 12.8 MB
    int* row_start   = (int*)ws;     ws += (size_t)(NN + 16) * sizeof(int);
    int* blockcnt    = (int*)ws;     ws += (size_t)(SCANA_N + 16) * sizeof(int);
    int* rowsum      = (int*)ws;     ws += (size_t)(NPART3 + 16) * sizeof(int);
    int* csr         = (int*)ws;                                              // 5 MB

    // packed edge bucket reuses the agg4 region (dead until first agg_kernel)
    int* ebufP = (int*)agg4;                     // NE ints = 5 MB <= 12.8 MB

    cast_kernel<<<(NN * DD / 4) / 256, 256, 0, stream>>>(x, hh4);

    countA_kernel<<<NTB, 256, 0, stream>>>(dst, blockcnt);
    scanP1_kernel<<<NPART3, 512, 0, stream>>>(blockcnt, rowsum);
    scanP2_kernel<<<1, 256, 0, stream>>>(rowsum);
    scatterA_kernel<<<NTB, 256, 0, stream>>>(src, dst, blockcnt, rowsum, ebufP);
    fillD_kernel<<<NPART3, 1024, 0, stream>>>(ebufP, rowsum, row_start, csr);

    for (int l = 0; l < NL; ++l) {
        agg_kernel<<<dim3(NN / 16, 4), 256, 0, stream>>>(hh4, row_start, csr, agg4);
        layer_mfma_kernel<<<L2BLOCKS, 256, 0, stream>>>(
            agg4, hh4, h, Wl + (size_t)l * DD * DD, bl + (size_t)l * DD, Wr + (size_t)l * DD * DD,
            (l == NL - 1) ? 1 : 0);
    }
}

// Round 5
// 267.393 us; speedup vs baseline: 1.3411x; 1.3411x over previous
//
#include <hip/hip_runtime.h>
#include <hip/hip_fp16.h>
#include <stdint.h>

#define NN 100000
#define NE 1250000
#define DD 64
#define NL 4

#define NPART3 256           // partitions; one WG owns one partition in fillD
#define PSIZE3 391           // nodes per partition (256*391 = 100096 >= NN)
#define TILE4 1024           // int4s per radix tile = 4096 edges
#define NTB ((NE / 4 + TILE4 - 1) / TILE4)        // 306 tiles
#define SCANA_N (NPART3 * NTB)                    // 78336
#define SRCBITS 17           // src < 100000 < 2^17; dlocal < 391 < 2^9

#define MB2 64               // nodes per MFMA layer block
#define L2BLOCKS ((NN + MB2 - 1) / MB2)   // 1563
#define APAD 136             // halfs per A/Bt LDS row
#define CPADH 72             // halfs per C row
#define CPADF 68             // floats per C row

typedef _Float16 half8 __attribute__((ext_vector_type(8)));
typedef _Float16 half2v __attribute__((ext_vector_type(2)));
typedef float floatx4 __attribute__((ext_vector_type(4)));
typedef int intx4 __attribute__((ext_vector_type(4)));

__device__ __forceinline__ unsigned f2h2(float a, float b) {
    __half2 h = __floats2half2_rn(a, b);
    return *reinterpret_cast<unsigned*>(&h);
}
// packed fp16 max on raw bits (maps to v_pk_max_f16)
__device__ __forceinline__ unsigned umax2(unsigned a, unsigned b) {
    half2v x = *reinterpret_cast<half2v*>(&a);
    half2v y = *reinterpret_cast<half2v*>(&b);
    half2v r = __builtin_elementwise_max(x, y);
    return *reinterpret_cast<unsigned*>(&r);
}
__device__ __forceinline__ void umax4(uint4& a, uint4 u) {
    a.x = umax2(a.x, u.x); a.y = umax2(a.y, u.y);
    a.z = umax2(a.z, u.z); a.w = umax2(a.w, u.w);
}

// ---- x (fp32) -> hh (fp16) ----
__global__ __launch_bounds__(256) void cast_kernel(const float* __restrict__ x,
                                                   __half* __restrict__ hh) {
    int i = blockIdx.x * 256 + threadIdx.x;
    float4 v = ((const float4*)x)[i];
    uint2 u;
    u.x = f2h2(v.x, v.y);
    u.y = f2h2(v.z, v.w);
    ((uint2*)hh)[i] = u;
}

// ---------------- radix bucketing: edges -> 256 dst-partition buckets ----------------
__global__ __launch_bounds__(256) void countA_kernel(const int* __restrict__ dst,
                                                     int* __restrict__ blockcnt) {
    __shared__ int cnt[NPART3];
    int tid = threadIdx.x;
    cnt[tid] = 0;
    __syncthreads();
    int b = blockIdx.x;
    #pragma unroll
    for (int r = 0; r < 4; ++r) {
        int i4 = b * TILE4 + r * 256 + tid;
        if (i4 < NE / 4) {
            intx4 d = __builtin_nontemporal_load(&((const intx4*)dst)[i4]);
            atomicAdd(&cnt[(unsigned)d.x / PSIZE3], 1);
            atomicAdd(&cnt[(unsigned)d.y / PSIZE3], 1);
            atomicAdd(&cnt[(unsigned)d.z / PSIZE3], 1);
            atomicAdd(&cnt[(unsigned)d.w / PSIZE3], 1);
        }
    }
    __syncthreads();
    blockcnt[tid * NTB + b] = cnt[tid];
}

// ---- parallel scan, stage 1: each WG exclusive-scans its own 306-tile row ----
__global__ __launch_bounds__(512) void scanP1_kernel(int* __restrict__ blockcnt,
                                                     int* __restrict__ rowsum) {
    __shared__ int sm[512];
    int p = blockIdx.x;
    int tid = threadIdx.x;
    int v = (tid < NTB) ? blockcnt[p * NTB + tid] : 0;
    sm[tid] = v;
    __syncthreads();
    for (int off = 1; off < 512; off <<= 1) {
        int t = (tid >= off) ? sm[tid - off] : 0;
        __syncthreads();
        sm[tid] += t;
        __syncthreads();
    }
    if (tid < NTB) blockcnt[p * NTB + tid] = sm[tid] - v;   // exclusive in-row
    if (tid == 511) rowsum[p] = sm[511];                    // row total
}

// ---- parallel scan, stage 2: exclusive scan of the 256 row totals (in place) ----
__global__ __launch_bounds__(256) void scanP2_kernel(int* __restrict__ rowsum) {
    __shared__ int sm[256];
    int tid = threadIdx.x;
    int v = rowsum[tid];
    sm[tid] = v;
    __syncthreads();
    for (int off = 1; off < 256; off <<= 1) {
        int t = (tid >= off) ? sm[tid - off] : 0;
        __syncthreads();
        sm[tid] += t;
        __syncthreads();
    }
    rowsum[tid] = sm[tid] - v;    // rowoff: global start of partition tid
}

// scatter packed (dlocal<<17 | src) into bucket order — one store per edge
__global__ __launch_bounds__(256) void scatterA_kernel(const int* __restrict__ src,
                                                       const int* __restrict__ dst,
                                                       const int* __restrict__ blockcnt,
                                                       const int* __restrict__ rowoff,
                                                       int* __restrict__ ebufP) {
    __shared__ int cur[NPART3];
    int tid = threadIdx.x;
    int b = blockIdx.x;
    cur[tid] = rowoff[tid] + blockcnt[tid * NTB + b];
    __syncthreads();
    #pragma unroll
    for (int r = 0; r < 4; ++r) {
        int i4 = b * TILE4 + r * 256 + tid;
        if (i4 < NE / 4) {
            intx4 d = __builtin_nontemporal_load(&((const intx4*)dst)[i4]);
            intx4 s = __builtin_nontemporal_load(&((const intx4*)src)[i4]);
            int part, p;
            part = (unsigned)d.x / PSIZE3; p = atomicAdd(&cur[part], 1);
            ebufP[p] = ((d.x - part * PSIZE3) << SRCBITS) | s.x;
            part = (unsigned)d.y / PSIZE3; p = atomicAdd(&cur[part], 1);
            ebufP[p] = ((d.y - part * PSIZE3) << SRCBITS) | s.y;
            part = (unsigned)d.z / PSIZE3; p = atomicAdd(&cur[part], 1);
            ebufP[p] = ((d.z - part * PSIZE3) << SRCBITS) | s.z;
            part = (unsigned)d.w / PSIZE3; p = atomicAdd(&cur[part], 1);
            ebufP[p] = ((d.w - part * PSIZE3) << SRCBITS) | s.w;
        }
    }
}

// ---- one WG per partition: LDS hist -> in-WG scan -> row_start + csr ----
__global__ __launch_bounds__(1024) void fillD_kernel(const int* __restrict__ ebufP,
                                                     const int* __restrict__ rowoff,
                                                     int* __restrict__ row_start,
                                                     int* __restrict__ csr) {
    __shared__ int cnt[PSIZE3];
    __shared__ int localstart[PSIZE3];
    __shared__ int partial[1024];
    int part = blockIdx.x;
    int tid = threadIdx.x;
    int nbase = part * PSIZE3;
    int base = rowoff[part];
    int hi = (part < NPART3 - 1) ? rowoff[part + 1] : NE;

    if (tid < PSIZE3) cnt[tid] = 0;
    __syncthreads();

    for (int i = base + tid; i < hi; i += 1024)
        atomicAdd(&cnt[(unsigned)ebufP[i] >> SRCBITS], 1);
    __syncthreads();

    int e0 = (tid < PSIZE3) ? cnt[tid] : 0;
    int s = e0;
    partial[tid] = s;
    __syncthreads();
    for (int off = 1; off < 1024; off <<= 1) {
        int v = (tid >= off) ? partial[tid - off] : 0;
        __syncthreads();
        partial[tid] += v;
        __syncthreads();
    }
    int run = partial[tid] - s;
    if (tid < PSIZE3) localstart[tid] = run;
    __syncthreads();

    int nmax = NN - nbase; if (nmax > PSIZE3) nmax = PSIZE3;
    if (tid < nmax) row_start[nbase + tid] = base + localstart[tid];
    if (part == NPART3 - 1 && tid == 0) row_start[NN] = NE;

    if (tid < PSIZE3) cnt[tid] = 0;
    __syncthreads();

    for (int i = base + tid; i < hi; i += 1024) {
        int p = ebufP[i];
        int dl = (unsigned)p >> SRCBITS;
        int local = atomicAdd(&cnt[dl], 1);
        csr[base + localstart[dl] + local] = p & ((1 << SRCBITS) - 1);
    }
}

// ---------------- per-layer gather-max: FOUR nodes per wave, branchless ----------------
// Latency x concurrency regime: 8 independent 16B gathers in flight per iteration
// (2 per node x 4 nodes) + 4 csr preloads. Slot indices are CLAMPED to the last
// neighbor instead of guarded: duplicate rows are no-ops under max and hit L1.
// Empty nodes (P ~ 4e-6) resolved by a final uniform select to 0.
__global__ __launch_bounds__(256, 6) void agg_kernel(const __half* __restrict__ hh,
                                                     const int* __restrict__ row_start,
                                                     const int* __restrict__ csr,
                                                     __half* __restrict__ aggh) {
    int tid = threadIdx.x;
    int wv = tid >> 6;
    int lane = tid & 63;
    int g = lane >> 3;              // neighbor sub-slot 0..7
    int c8 = (lane & 7) * 8;        // column base (halfs)
    int nb = blockIdx.x * 16 + wv * 4;   // NN = 6250*16 exactly

    int rsl = row_start[nb + ((lane < 5) ? lane : 4)];
    int base0 = __builtin_amdgcn_readlane(rsl, 0);
    int base1 = __builtin_amdgcn_readlane(rsl, 1);
    int base2 = __builtin_amdgcn_readlane(rsl, 2);
    int base3 = __builtin_amdgcn_readlane(rsl, 3);
    int end3  = __builtin_amdgcn_readlane(rsl, 4);
    int cnt0 = base1 - base0, cnt1 = base2 - base1;
    int cnt2 = base3 - base2, cnt3 = end3 - base3;
    // clamped last-slot (>=0 even for empty nodes)
    int cl0 = max(cnt0 - 1, 0), cl1 = max(cnt1 - 1, 0);
    int cl2 = max(cnt2 - 1, 0), cl3 = max(cnt3 - 1, 0);

    // csr index preloads for 4 nodes (independent, coalesced, always in-bounds)
    int idx0 = csr[min(base0, NE - 1) + min(lane, cl0)];
    int idx1 = csr[min(base1, NE - 1) + min(lane, cl1)];
    int idx2 = csr[min(base2, NE - 1) + min(lane, cl2)];
    int idx3 = csr[min(base3, NE - 1) + min(lane, cl3)];

    const uint4 NI4 = make_uint4(0xFC00FC00u, 0xFC00FC00u, 0xFC00FC00u, 0xFC00FC00u);
    uint4 acc0 = NI4, acc1 = NI4, acc2 = NI4, acc3 = NI4;

    int m0 = min(cnt0, 64), m1 = min(cnt1, 64);
    int m2 = min(cnt2, 64), m3 = min(cnt3, 64);
    int km = max(max(m0, m1), max(m2, m3));

    for (int k = 0; k < km; k += 16) {
        int ka = k + g;
        int kb = ka + 8;
        // clamped slot -> source node ids (8 shuffles)
        int a0 = __shfl(idx0, min(ka, cl0), 64);
        int b0 = __shfl(idx0, min(kb, cl0), 64);
        int a1 = __shfl(idx1, min(ka, cl1), 64);
        int b1 = __shfl(idx1, min(kb, cl1), 64);
        int a2 = __shfl(idx2, min(ka, cl2), 64);
        int b2 = __shfl(idx2, min(kb, cl2), 64);
        int a3 = __shfl(idx3, min(ka, cl3), 64);
        int b3 = __shfl(idx3, min(kb, cl3), 64);
        // 8 unconditional independent loads (dups harmless under max)
        uint4 u0 = *(const uint4*)&hh[(unsigned)a0 * DD + c8];
        uint4 u1 = *(const uint4*)&hh[(unsigned)a1 * DD + c8];
        uint4 u2 = *(const uint4*)&hh[(unsigned)a2 * DD + c8];
        uint4 u3 = *(const uint4*)&hh[(unsigned)a3 * DD + c8];
        uint4 v0 = *(const uint4*)&hh[(unsigned)b0 * DD + c8];
        uint4 v1 = *(const uint4*)&hh[(unsigned)b1 * DD + c8];
        uint4 v2 = *(const uint4*)&hh[(unsigned)b2 * DD + c8];
        uint4 v3 = *(const uint4*)&hh[(unsigned)b3 * DD + c8];
        umax4(acc0, u0); umax4(acc1, u1); umax4(acc2, u2); umax4(acc3, u3);
        umax4(acc0, v0); umax4(acc1, v1); umax4(acc2, v2); umax4(acc3, v3);
    }

    // ultra-rare tails (cnt > 64)
    if (cnt0 > 64) for (int k = 64 + g; k < cnt0; k += 8) {
        int s = csr[base0 + k];
        uint4 u = *(const uint4*)&hh[(unsigned)s * DD + c8];
        umax4(acc0, u);
    }
    if (cnt1 > 64) for (int k = 64 + g; k < cnt1; k += 8) {
        int s = csr[base1 + k];
        uint4 u = *(const uint4*)&hh[(unsigned)s * DD + c8];
        umax4(acc1, u);
    }
    if (cnt2 > 64) for (int k = 64 + g; k < cnt2; k += 8) {
        int s = csr[base2 + k];
        uint4 u = *(const uint4*)&hh[(unsigned)s * DD + c8];
        umax4(acc2, u);
    }
    if (cnt3 > 64) for (int k = 64 + g; k < cnt3; k += 8) {
        int s = csr[base3 + k];
        uint4 u = *(const uint4*)&hh[(unsigned)s * DD + c8];
        umax4(acc3, u);
    }

    // cross-slot reduce (xor 8/16/32) in packed half2, 4 nodes
    #pragma unroll
    for (int off = 8; off <= 32; off <<= 1) {
        acc0.x = umax2(acc0.x, (unsigned)__shfl_xor((int)acc0.x, off, 64));
        acc0.y = umax2(acc0.y, (unsigned)__shfl_xor((int)acc0.y, off, 64));
        acc0.z = umax2(acc0.z, (unsigned)__shfl_xor((int)acc0.z, off, 64));
        acc0.w = umax2(acc0.w, (unsigned)__shfl_xor((int)acc0.w, off, 64));
        acc1.x = umax2(acc1.x, (unsigned)__shfl_xor((int)acc1.x, off, 64));
        acc1.y = umax2(acc1.y, (unsigned)__shfl_xor((int)acc1.y, off, 64));
        acc1.z = umax2(acc1.z, (unsigned)__shfl_xor((int)acc1.z, off, 64));
        acc1.w = umax2(acc1.w, (unsigned)__shfl_xor((int)acc1.w, off, 64));
        acc2.x = umax2(acc2.x, (unsigned)__shfl_xor((int)acc2.x, off, 64));
        acc2.y = umax2(acc2.y, (unsigned)__shfl_xor((int)acc2.y, off, 64));
        acc2.z = umax2(acc2.z, (unsigned)__shfl_xor((int)acc2.z, off, 64));
        acc2.w = umax2(acc2.w, (unsigned)__shfl_xor((int)acc2.w, off, 64));
        acc3.x = umax2(acc3.x, (unsigned)__shfl_xor((int)acc3.x, off, 64));
        acc3.y = umax2(acc3.y, (unsigned)__shfl_xor((int)acc3.y, off, 64));
        acc3.z = umax2(acc3.z, (unsigned)__shfl_xor((int)acc3.z, off, 64));
        acc3.w = umax2(acc3.w, (unsigned)__shfl_xor((int)acc3.w, off, 64));
    }

    const uint4 Z4 = make_uint4(0, 0, 0, 0);
    if (cnt0 <= 0) acc0 = Z4;
    if (cnt1 <= 0) acc1 = Z4;
    if (cnt2 <= 0) acc2 = Z4;
    if (cnt3 <= 0) acc3 = Z4;

    if (lane < 8) {
        *(uint4*)&aggh[(size_t)(nb + 0) * DD + c8] = acc0;
        *(uint4*)&aggh[(size_t)(nb + 1) * DD + c8] = acc1;
        *(uint4*)&aggh[(size_t)(nb + 2) * DD + c8] = acc2;
        *(uint4*)&aggh[(size_t)(nb + 3) * DD + c8] = acc3;
    }
}

// ---------------- dense update via MFMA ----------------
__global__ __launch_bounds__(256, 4) void layer_mfma_kernel(
        const __half* __restrict__ aggh,
        __half* __restrict__ hh,
        float* __restrict__ hout,
        const float* __restrict__ Wl,
        const float* __restrict__ bl,
        const float* __restrict__ Wr,
        int last) {
    __shared__ char smem[2 * MB2 * APAD * 2];   // 34816 B, reused by epilogue
    _Float16* a_s  = (_Float16*)smem;                          // [64][APAD]
    _Float16* bt_s = (_Float16*)(smem + MB2 * APAD * 2);       // [64][APAD], n-major

    int tid = threadIdx.x;
    int lane = tid & 63;
    int w = tid >> 6;
    int node0 = blockIdx.x * MB2;

    #pragma unroll
    for (int i = 0; i < 4; ++i) {
        int idx = i * 256 + tid;          // uint4 id, 1024 total
        int r = idx >> 4;
        int c4 = idx & 15;
        int node = node0 + r; if (node > NN - 1) node = NN - 1;
        const __half* srcp = (c4 < 8) ? (aggh + (size_t)node * DD + c4 * 8)
                                      : (hh + (size_t)node * DD + (c4 - 8) * 8);
        uint4 v = *(const uint4*)srcp;
        *(uint4*)&a_s[r * APAD + c4 * 8] = v;
    }
    {
        int n = tid & 63;
        int kb = tid >> 6;
        #pragma unroll
        for (int kk = 0; kk < 32; ++kk) {
            int k = kb * 32 + kk;
            float wv = (k < 64) ? Wl[k * DD + n] : Wr[(k - 64) * DD + n];
            bt_s[n * APAD + k] = (_Float16)wv;
        }
    }
    __syncthreads();

    floatx4 acc[4];
    #pragma unroll
    for (int nt = 0; nt < 4; ++nt) acc[nt] = (floatx4){0.f, 0.f, 0.f, 0.f};
    int m = lane & 15;
    int q = lane >> 4;

    #pragma unroll
    for (int ks = 0; ks < 4; ++ks) {
        half8 af = *(half8*)&a_s[(w * 16 + m) * APAD + q * 8 + ks * 32];
        #pragma unroll
        for (int nt = 0; nt < 4; ++nt) {
            half8 bf = *(half8*)&bt_s[(nt * 16 + m) * APAD + q * 8 + ks * 32];
            acc[nt] = __builtin_amdgcn_mfma_f32_16x16x32_f16(af, bf, acc[nt], 0, 0, 0);
        }
    }
    __syncthreads();

    _Float16* ch = (_Float16*)smem;                      // [64][CPADH]
    float*    cf = (float*)(smem + MB2 * CPADH * 2);     // [64][CPADF]

    #pragma unroll
    for (int nt = 0; nt < 4; ++nt) {
        int col = nt * 16 + m;
        float b = bl[col];
        #pragma unroll
        for (int r = 0; r < 4; ++r) {
            int rowl = w * 16 + q * 4 + r;
            float o = fmaxf(acc[nt][r] + b, 0.0f);
            if (last) cf[rowl * CPADF + col] = o;
            else      ch[rowl * CPADH + col] = (_Float16)o;
        }
    }
    __syncthreads();

    if (!last) {
        #pragma unroll
        for (int i = 0; i < 2; ++i) {
            int idx = i * 256 + tid;          // 512 uint4s
            int r = idx >> 3;
            int c4 = idx & 7;
            int node = node0 + r;
            if (node < NN) {
                uint4 v = *(uint4*)&ch[r * CPADH + c4 * 8];
                *(uint4*)&hh[(size_t)node * DD + c4 * 8] = v;
            }
        }
    } else {
        #pragma unroll
        for (int i = 0; i < 4; ++i) {
            int idx = i * 256 + tid;      // 1024 float4s
            int r = idx >> 4;
            int c4 = idx & 15;
            int node = node0 + r;
            if (node < NN) {
                float4 v = *(float4*)&cf[r * CPADF + c4 * 4];
                *(float4*)&hout[(size_t)node * DD + c4 * 4] = v;
            }
        }
    }
}

extern "C" void kernel_launch(void* const* d_in, const int* in_sizes, int n_in,
                              void* d_out, int out_size, void* d_ws, size_t ws_size,
                              hipStream_t stream) {
    const float* x  = (const float*)d_in[0];
    const int*   ei = (const int*)d_in[1];
    const float* Wl = (const float*)d_in[2];
    const float* bl = (const float*)d_in[3];
    const float* Wr = (const float*)d_in[4];
    float* h = (float*)d_out;

    const int* src = ei;
    const int* dst = ei + NE;

    char* ws = (char*)d_ws;
    __half* aggh     = (__half*)ws;  ws += (size_t)NN * DD * sizeof(__half);  // 12.8 MB
    __half* hh       = (__half*)ws;  ws += (size_t)NN * DD * sizeof(__half);  // 12.8 MB
    int* row_start   = (int*)ws;     ws += (size_t)(NN + 16) * sizeof(int);
    int* blockcnt    = (int*)ws;     ws += (size_t)(SCANA_N + 16) * sizeof(int);
    int* rowsum      = (int*)ws;     ws += (size_t)(NPART3 + 16) * sizeof(int);
    int* csr         = (int*)ws;                                              // 5 MB

    // packed edge bucket reuses the aggh region (dead until first agg_kernel)
    int* ebufP = (int*)aggh;                     // NE ints = 5 MB <= 12.8 MB

    cast_kernel<<<(NN * DD / 4) / 256, 256, 0, stream>>>(x, hh);

    countA_kernel<<<NTB, 256, 0, stream>>>(dst, blockcnt);
    scanP1_kernel<<<NPART3, 512, 0, stream>>>(blockcnt, rowsum);
    scanP2_kernel<<<1, 256, 0, stream>>>(rowsum);
    scatterA_kernel<<<NTB, 256, 0, stream>>>(src, dst, blockcnt, rowsum, ebufP);
    fillD_kernel<<<NPART3, 1024, 0, stream>>>(ebufP, rowsum, row_start, csr);

    for (int l = 0; l < NL; ++l) {
        agg_kernel<<<NN / 16, 256, 0, stream>>>(hh, row_start, csr, aggh);
        layer_mfma_kernel<<<L2BLOCKS, 256, 0, stream>>>(
            aggh, hh, h, Wl + (size_t)l * DD * DD, bl + (size_t)l * DD, Wr + (size_t)l * DD * DD,
            (l == NL - 1) ? 1 : 0);
    }
}

// Round 6
// 257.092 us; speedup vs baseline: 1.3948x; 1.0401x over previous
//
#include <hip/hip_runtime.h>
#include <hip/hip_fp16.h>
#include <stdint.h>

#define NN 100000
#define NE 1250000
#define DD 64
#define NL 4

#define NPART3 256           // partitions; one WG owns one partition in fillD
#define PSIZE3 391           // nodes per partition (256*391 = 100096 >= NN)
#define TILE4 1024           // int4s per radix tile = 4096 edges
#define NTB ((NE / 4 + TILE4 - 1) / TILE4)        // 306 tiles
#define SCANA_N (NPART3 * NTB)                    // 78336
#define SRCBITS 17           // src < 100000 < 2^17; dlocal < 391 < 2^9

#define MB2 64               // nodes per MFMA layer block
#define L2BLOCKS ((NN + MB2 - 1) / MB2)   // 1563
#define APAD 136             // halfs per A/Bt LDS row
#define CPADH 72             // halfs per C row
#define CPADF 68             // floats per C row

typedef _Float16 half8 __attribute__((ext_vector_type(8)));
typedef _Float16 half2v __attribute__((ext_vector_type(2)));
typedef float floatx4 __attribute__((ext_vector_type(4)));
typedef int intx4 __attribute__((ext_vector_type(4)));

__device__ __forceinline__ unsigned f2h2(float a, float b) {
    __half2 h = __floats2half2_rn(a, b);
    return *reinterpret_cast<unsigned*>(&h);
}
// packed fp16 max on raw bits (maps to v_pk_max_f16)
__device__ __forceinline__ unsigned umax2(unsigned a, unsigned b) {
    half2v x = *reinterpret_cast<half2v*>(&a);
    half2v y = *reinterpret_cast<half2v*>(&b);
    half2v r = __builtin_elementwise_max(x, y);
    return *reinterpret_cast<unsigned*>(&r);
}
__device__ __forceinline__ void umax4(uint4& a, uint4 u) {
    a.x = umax2(a.x, u.x); a.y = umax2(a.y, u.y);
    a.z = umax2(a.z, u.z); a.w = umax2(a.w, u.w);
}

// ---- x (fp32) -> hh (fp16) ----
__global__ __launch_bounds__(256) void cast_kernel(const float* __restrict__ x,
                                                   __half* __restrict__ hh) {
    int i = blockIdx.x * 256 + threadIdx.x;
    float4 v = ((const float4*)x)[i];
    uint2 u;
    u.x = f2h2(v.x, v.y);
    u.y = f2h2(v.z, v.w);
    ((uint2*)hh)[i] = u;
}

// ---------------- radix bucketing: edges -> 256 dst-partition buckets ----------------
__global__ __launch_bounds__(256) void countA_kernel(const int* __restrict__ dst,
                                                     int* __restrict__ blockcnt) {
    __shared__ int cnt[NPART3];
    int tid = threadIdx.x;
    cnt[tid] = 0;
    __syncthreads();
    int b = blockIdx.x;
    #pragma unroll
    for (int r = 0; r < 4; ++r) {
        int i4 = b * TILE4 + r * 256 + tid;
        if (i4 < NE / 4) {
            intx4 d = __builtin_nontemporal_load(&((const intx4*)dst)[i4]);
            atomicAdd(&cnt[(unsigned)d.x / PSIZE3], 1);
            atomicAdd(&cnt[(unsigned)d.y / PSIZE3], 1);
            atomicAdd(&cnt[(unsigned)d.z / PSIZE3], 1);
            atomicAdd(&cnt[(unsigned)d.w / PSIZE3], 1);
        }
    }
    __syncthreads();
    blockcnt[tid * NTB + b] = cnt[tid];
}

// ---- parallel scan, stage 1: each WG exclusive-scans its own 306-tile row ----
__global__ __launch_bounds__(512) void scanP1_kernel(int* __restrict__ blockcnt,
                                                     int* __restrict__ rowsum) {
    __shared__ int sm[512];
    int p = blockIdx.x;
    int tid = threadIdx.x;
    int v = (tid < NTB) ? blockcnt[p * NTB + tid] : 0;
    sm[tid] = v;
    __syncthreads();
    for (int off = 1; off < 512; off <<= 1) {
        int t = (tid >= off) ? sm[tid - off] : 0;
        __syncthreads();
        sm[tid] += t;
        __syncthreads();
    }
    if (tid < NTB) blockcnt[p * NTB + tid] = sm[tid] - v;   // exclusive in-row
    if (tid == 511) rowsum[p] = sm[511];                    // row total
}

// ---- parallel scan, stage 2: exclusive scan of the 256 row totals (in place) ----
__global__ __launch_bounds__(256) void scanP2_kernel(int* __restrict__ rowsum) {
    __shared__ int sm[256];
    int tid = threadIdx.x;
    int v = rowsum[tid];
    sm[tid] = v;
    __syncthreads();
    for (int off = 1; off < 256; off <<= 1) {
        int t = (tid >= off) ? sm[tid - off] : 0;
        __syncthreads();
        sm[tid] += t;
        __syncthreads();
    }
    rowsum[tid] = sm[tid] - v;    // rowoff: global start of partition tid
}

// scatter packed (dlocal<<17 | src) into bucket order — one store per edge
__global__ __launch_bounds__(256) void scatterA_kernel(const int* __restrict__ src,
                                                       const int* __restrict__ dst,
                                                       const int* __restrict__ blockcnt,
                                                       const int* __restrict__ rowoff,
                                                       int* __restrict__ ebufP) {
    __shared__ int cur[NPART3];
    int tid = threadIdx.x;
    int b = blockIdx.x;
    cur[tid] = rowoff[tid] + blockcnt[tid * NTB + b];
    __syncthreads();
    #pragma unroll
    for (int r = 0; r < 4; ++r) {
        int i4 = b * TILE4 + r * 256 + tid;
        if (i4 < NE / 4) {
            intx4 d = __builtin_nontemporal_load(&((const intx4*)dst)[i4]);
            intx4 s = __builtin_nontemporal_load(&((const intx4*)src)[i4]);
            int part, p;
            part = (unsigned)d.x / PSIZE3; p = atomicAdd(&cur[part], 1);
            ebufP[p] = ((d.x - part * PSIZE3) << SRCBITS) | s.x;
            part = (unsigned)d.y / PSIZE3; p = atomicAdd(&cur[part], 1);
            ebufP[p] = ((d.y - part * PSIZE3) << SRCBITS) | s.y;
            part = (unsigned)d.z / PSIZE3; p = atomicAdd(&cur[part], 1);
            ebufP[p] = ((d.z - part * PSIZE3) << SRCBITS) | s.z;
            part = (unsigned)d.w / PSIZE3; p = atomicAdd(&cur[part], 1);
            ebufP[p] = ((d.w - part * PSIZE3) << SRCBITS) | s.w;
        }
    }
}

// ---- one WG per partition: LDS hist -> in-WG scan -> row_start + csr ----
__global__ __launch_bounds__(1024) void fillD_kernel(const int* __restrict__ ebufP,
                                                     const int* __restrict__ rowoff,
                                                     int* __restrict__ row_start,
                                                     int* __restrict__ csr) {
    __shared__ int cnt[PSIZE3];
    __shared__ int localstart[PSIZE3];
    __shared__ int partial[1024];
    int part = blockIdx.x;
    int tid = threadIdx.x;
    int nbase = part * PSIZE3;
    int base = rowoff[part];
    int hi = (part < NPART3 - 1) ? rowoff[part + 1] : NE;

    if (tid < PSIZE3) cnt[tid] = 0;
    __syncthreads();

    for (int i = base + tid; i < hi; i += 1024)
        atomicAdd(&cnt[(unsigned)ebufP[i] >> SRCBITS], 1);
    __syncthreads();

    int e0 = (tid < PSIZE3) ? cnt[tid] : 0;
    int s = e0;
    partial[tid] = s;
    __syncthreads();
    for (int off = 1; off < 1024; off <<= 1) {
        int v = (tid >= off) ? partial[tid - off] : 0;
        __syncthreads();
        partial[tid] += v;
        __syncthreads();
    }
    int run = partial[tid] - s;
    if (tid < PSIZE3) localstart[tid] = run;
    __syncthreads();

    int nmax = NN - nbase; if (nmax > PSIZE3) nmax = PSIZE3;
    if (tid < nmax) row_start[nbase + tid] = base + localstart[tid];
    if (part == NPART3 - 1 && tid == 0) row_start[NN] = NE;

    if (tid < PSIZE3) cnt[tid] = 0;
    __syncthreads();

    for (int i = base + tid; i < hi; i += 1024) {
        int p = ebufP[i];
        int dl = (unsigned)p >> SRCBITS;
        int local = atomicAdd(&cnt[dl], 1);
        csr[base + localstart[dl] + local] = p & ((1 << SRCBITS) - 1);
    }
}

// ---------------- per-layer gather-max: TRANSPOSED lanes, zero reduce ----------------
// lane = (node_local 0..7)*8 + chunk 0..7: each lane owns one 16B column chunk of
// one node and serially maxes over ALL its neighbors. No cross-lane reduce at all.
// One load instruction per iteration covers 8 full 128B rows (8 edges). csr
// indices consumed 8-at-a-time with a clamped prefetch of the next block (hides
// index-load latency under the gathers). Clamped duplicate slots are L1 hits.
__global__ __launch_bounds__(256, 6) void agg_kernel(const __half* __restrict__ hh,
                                                     const int* __restrict__ row_start,
                                                     const int* __restrict__ csr,
                                                     __half* __restrict__ aggh) {
    int tid = threadIdx.x;
    int wv = tid >> 6;
    int lane = tid & 63;
    int nl = lane >> 3;             // node_local 0..7
    int l8 = lane & 7;              // column chunk 0..7
    int c8 = l8 * 8;                // halfs offset of this lane's 16B chunk
    int nb = blockIdx.x * 32 + wv * 8;   // NN = 3125*32 exactly

    // row_start for nodes nb..nb+8 via one coalesced load + shuffles
    int rsl = row_start[nb + ((lane < 9) ? lane : 8)];
    int base = __shfl(rsl, nl, 64);
    int cnt  = __shfl(rsl, nl + 1, 64) - base;
    int cl   = max(cnt - 1, 0);
    int bclamp = min(base, NE - 1);

    // wave-wide max degree (cnt uniform within each 8-lane group)
    int km = cnt;
    km = max(km, __shfl_xor(km, 8, 64));
    km = max(km, __shfl_xor(km, 16, 64));
    km = max(km, __shfl_xor(km, 32, 64));

    const uint4 NI4 = make_uint4(0xFC00FC00u, 0xFC00FC00u, 0xFC00FC00u, 0xFC00FC00u);
    uint4 acc = NI4;
    int lsrc = lane & 56;           // node_local*8: shfl source base

    // preload first index block (8 indices per node, clamped)
    int idx = csr[bclamp + min(l8, cl)];
    for (int k0 = 0; k0 < km; k0 += 8) {
        // prefetch next block (clamped -> always safe, overlaps with gathers)
        int nidx = csr[bclamp + min(k0 + 8 + l8, cl)];
        #pragma unroll
        for (int j = 0; j < 8; ++j) {
            int srcv = __shfl(idx, lsrc + j, 64);
            uint4 u = *(const uint4*)&hh[(unsigned)srcv * DD + c8];
            umax4(acc, u);
        }
        idx = nidx;
    }

    if (cnt <= 0) acc = make_uint4(0, 0, 0, 0);
    // fully coalesced: 64 lanes = 8 complete rows (1 KB)
    *(uint4*)&aggh[(size_t)(nb + nl) * DD + c8] = acc;
}

// ---------------- dense update via MFMA ----------------
__global__ __launch_bounds__(256, 4) void layer_mfma_kernel(
        const __half* __restrict__ aggh,
        __half* __restrict__ hh,
        float* __restrict__ hout,
        const float* __restrict__ Wl,
        const float* __restrict__ bl,
        const float* __restrict__ Wr,
        int last) {
    __shared__ char smem[2 * MB2 * APAD * 2];   // 34816 B, reused by epilogue
    _Float16* a_s  = (_Float16*)smem;                          // [64][APAD]
    _Float16* bt_s = (_Float16*)(smem + MB2 * APAD * 2);       // [64][APAD], n-major

    int tid = threadIdx.x;
    int lane = tid & 63;
    int w = tid >> 6;
    int node0 = blockIdx.x * MB2;

    #pragma unroll
    for (int i = 0; i < 4; ++i) {
        int idx = i * 256 + tid;          // uint4 id, 1024 total
        int r = idx >> 4;
        int c4 = idx & 15;
        int node = node0 + r; if (node > NN - 1) node = NN - 1;
        const __half* srcp = (c4 < 8) ? (aggh + (size_t)node * DD + c4 * 8)
                                      : (hh + (size_t)node * DD + (c4 - 8) * 8);
        uint4 v = *(const uint4*)srcp;
        *(uint4*)&a_s[r * APAD + c4 * 8] = v;
    }
    {
        int n = tid & 63;
        int kb = tid >> 6;
        #pragma unroll
        for (int kk = 0; kk < 32; ++kk) {
            int k = kb * 32 + kk;
            float wv = (k < 64) ? Wl[k * DD + n] : Wr[(k - 64) * DD + n];
            bt_s[n * APAD + k] = (_Float16)wv;
        }
    }
    __syncthreads();

    floatx4 acc[4];
    #pragma unroll
    for (int nt = 0; nt < 4; ++nt) acc[nt] = (floatx4){0.f, 0.f, 0.f, 0.f};
    int m = lane & 15;
    int q = lane >> 4;

    #pragma unroll
    for (int ks = 0; ks < 4; ++ks) {
        half8 af = *(half8*)&a_s[(w * 16 + m) * APAD + q * 8 + ks * 32];
        #pragma unroll
        for (int nt = 0; nt < 4; ++nt) {
            half8 bf = *(half8*)&bt_s[(nt * 16 + m) * APAD + q * 8 + ks * 32];
            acc[nt] = __builtin_amdgcn_mfma_f32_16x16x32_f16(af, bf, acc[nt], 0, 0, 0);
        }
    }
    __syncthreads();

    _Float16* ch = (_Float16*)smem;                      // [64][CPADH]
    float*    cf = (float*)(smem + MB2 * CPADH * 2);     // [64][CPADF]

    #pragma unroll
    for (int nt = 0; nt < 4; ++nt) {
        int col = nt * 16 + m;
        float b = bl[col];
        #pragma unroll
        for (int r = 0; r < 4; ++r) {
            int rowl = w * 16 + q * 4 + r;
            float o = fmaxf(acc[nt][r] + b, 0.0f);
            if (last) cf[rowl * CPADF + col] = o;
            else      ch[rowl * CPADH + col] = (_Float16)o;
        }
    }
    __syncthreads();

    if (!last) {
        #pragma unroll
        for (int i = 0; i < 2; ++i) {
            int idx = i * 256 + tid;          // 512 uint4s
            int r = idx >> 3;
            int c4 = idx & 7;
            int node = node0 + r;
            if (node < NN) {
                uint4 v = *(uint4*)&ch[r * CPADH + c4 * 8];
                *(uint4*)&hh[(size_t)node * DD + c4 * 8] = v;
            }
        }
    } else {
        #pragma unroll
        for (int i = 0; i < 4; ++i) {
            int idx = i * 256 + tid;      // 1024 float4s
            int r = idx >> 4;
            int c4 = idx & 15;
            int node = node0 + r;
            if (node < NN) {
                float4 v = *(float4*)&cf[r * CPADF + c4 * 4];
                *(float4*)&hout[(size_t)node * DD + c4 * 4] = v;
            }
        }
    }
}

extern "C" void kernel_launch(void* const* d_in, const int* in_sizes, int n_in,
                              void* d_out, int out_size, void* d_ws, size_t ws_size,
                              hipStream_t stream) {
    const float* x  = (const float*)d_in[0];
    const int*   ei = (const int*)d_in[1];
    const float* Wl = (const float*)d_in[2];
    const float* bl = (const float*)d_in[3];
    const float* Wr = (const float*)d_in[4];
    float* h = (float*)d_out;

    const int* src = ei;
    const int* dst = ei + NE;

    char* ws = (char*)d_ws;
    __half* aggh     = (__half*)ws;  ws += (size_t)NN * DD * sizeof(__half);  // 12.8 MB
    __half* hh       = (__half*)ws;  ws += (size_t)NN * DD * sizeof(__half);  // 12.8 MB
    int* row_start   = (int*)ws;     ws += (size_t)(NN + 16) * sizeof(int);
    int* blockcnt    = (int*)ws;     ws += (size_t)(SCANA_N + 16) * sizeof(int);
    int* rowsum      = (int*)ws;     ws += (size_t)(NPART3 + 16) * sizeof(int);
    int* csr         = (int*)ws;                                              // 5 MB

    // packed edge bucket reuses the aggh region (dead until first agg_kernel)
    int* ebufP = (int*)aggh;                     // NE ints = 5 MB <= 12.8 MB

    cast_kernel<<<(NN * DD / 4) / 256, 256, 0, stream>>>(x, hh);

    countA_kernel<<<NTB, 256, 0, stream>>>(dst, blockcnt);
    scanP1_kernel<<<NPART3, 512, 0, stream>>>(blockcnt, rowsum);
    scanP2_kernel<<<1, 256, 0, stream>>>(rowsum);
    scatterA_kernel<<<NTB, 256, 0, stream>>>(src, dst, blockcnt, rowsum, ebufP);
    fillD_kernel<<<NPART3, 1024, 0, stream>>>(ebufP, rowsum, row_start, csr);

    for (int l = 0; l < NL; ++l) {
        agg_kernel<<<NN / 32, 256, 0, stream>>>(hh, row_start, csr, aggh);
        layer_mfma_kernel<<<L2BLOCKS, 256, 0, stream>>>(
            aggh, hh, h, Wl + (size_t)l * DD * DD, bl + (size_t)l * DD, Wr + (size_t)l * DD * DD,
            (l == NL - 1) ? 1 : 0);
    }
}